// Round 1
// baseline (3838.760 us; speedup 1.0000x reference)
//
#include <hip/hip_runtime.h>
#include <hip/hip_bf16.h>
#include <stdint.h>

// B,S,H,I = 4,2048,4096,11008 ; M = B*S = 8192
static constexpr int Hd = 4096;
static constexpr int Id = 11008;
static constexpr int Md = 8192;

using short8 = __attribute__((ext_vector_type(8))) short;
using f32x4  = __attribute__((ext_vector_type(4))) float;

__device__ __forceinline__ unsigned short f2bf(float x) {
    union { float f; unsigned u; } v; v.f = x;
    unsigned r = v.u + 0x7FFF + ((v.u >> 16) & 1);   // RNE
    return (unsigned short)(r >> 16);
}

__device__ __forceinline__ void cvt_store(unsigned short* dst, const f32x4& a, const f32x4& b) {
    short8 v;
    v[0] = (short)f2bf(a[0]); v[1] = (short)f2bf(a[1]);
    v[2] = (short)f2bf(a[2]); v[3] = (short)f2bf(a[3]);
    v[4] = (short)f2bf(b[0]); v[5] = (short)f2bf(b[1]);
    v[6] = (short)f2bf(b[2]); v[7] = (short)f2bf(b[3]);
    *reinterpret_cast<short8*>(dst) = v;
}

// ---------------------------------------------------------------------------
// Kernel 1: inter[m,i] = silu(x·wg^T) * (x·wu^T)   (bf16 out to workspace)
// 128x128 tile over (M, I), K = Hd. 256 threads = 4 waves (2x2), 64x64/wave.
// ---------------------------------------------------------------------------
__global__ __launch_bounds__(256, 2) void k_gateup(
    const float* __restrict__ x, const float* __restrict__ wg,
    const float* __restrict__ wu, unsigned short* __restrict__ inter)
{
    __shared__ unsigned short As[2][4096];  // 128 x 32 bf16
    __shared__ unsigned short Gs[2][4096];
    __shared__ unsigned short Us[2][4096];

    const int tid = threadIdx.x;
    const int nwg = gridDim.x;                      // 5504, %8==0
    const int bid = blockIdx.x;
    const int swz = (bid & 7) * (nwg >> 3) + (bid >> 3);   // XCD swizzle
    const int m0 = (swz & 63) * 128;                // m fastest -> weight panel reuse
    const int n0 = (swz >> 6) * 128;

    const int lane = tid & 63;
    const int wid  = tid >> 6;
    const int wr   = (wid >> 1) << 6;   // wave row offset in tile
    const int wc   = (wid & 1) << 6;    // wave col offset
    const int r16  = lane & 15;
    const int kg   = lane >> 4;         // k-group 0..3

    // staging: thread handles 16B chunks {tid, tid+256}; chunk c -> row c>>2, col8 (c&3)*8
    const int srow = tid >> 2;
    const int sc8  = (tid & 3) * 8;
    const float* pa = x  + (size_t)(m0 + srow) * Hd + sc8;
    const float* pg = wg + (size_t)(n0 + srow) * Hd + sc8;
    const float* pu = wu + (size_t)(n0 + srow) * Hd + sc8;
    const size_t rstep = (size_t)64 * Hd;           // +64 rows (chunk 1)

    f32x4 accg[4][4] = {};
    f32x4 accu[4][4] = {};

    // prologue: stage k-tile 0 into buffer 0
    {
        f32x4 r0 = *(const f32x4*)(pa);         f32x4 r1 = *(const f32x4*)(pa + 4);
        f32x4 r2 = *(const f32x4*)(pa + rstep); f32x4 r3 = *(const f32x4*)(pa + rstep + 4);
        f32x4 r4 = *(const f32x4*)(pg);         f32x4 r5 = *(const f32x4*)(pg + 4);
        f32x4 r6 = *(const f32x4*)(pg + rstep); f32x4 r7 = *(const f32x4*)(pg + rstep + 4);
        f32x4 r8 = *(const f32x4*)(pu);         f32x4 r9 = *(const f32x4*)(pu + 4);
        f32x4 rA = *(const f32x4*)(pu + rstep); f32x4 rB = *(const f32x4*)(pu + rstep + 4);
        cvt_store(&As[0][tid * 8],        r0, r1);
        cvt_store(&As[0][tid * 8 + 2048], r2, r3);
        cvt_store(&Gs[0][tid * 8],        r4, r5);
        cvt_store(&Gs[0][tid * 8 + 2048], r6, r7);
        cvt_store(&Us[0][tid * 8],        r8, r9);
        cvt_store(&Us[0][tid * 8 + 2048], rA, rB);
    }
    __syncthreads();

    const int NK = Hd / 32;   // 128
    int cur = 0;
    for (int kt = 0; kt < NK; ++kt) {
        const bool more = (kt + 1) < NK;
        f32x4 r[12];
        if (more) {
            const int ko = (kt + 1) * 32;
            r[0]  = *(const f32x4*)(pa + ko);          r[1]  = *(const f32x4*)(pa + ko + 4);
            r[2]  = *(const f32x4*)(pa + rstep + ko);  r[3]  = *(const f32x4*)(pa + rstep + ko + 4);
            r[4]  = *(const f32x4*)(pg + ko);          r[5]  = *(const f32x4*)(pg + ko + 4);
            r[6]  = *(const f32x4*)(pg + rstep + ko);  r[7]  = *(const f32x4*)(pg + rstep + ko + 4);
            r[8]  = *(const f32x4*)(pu + ko);          r[9]  = *(const f32x4*)(pu + ko + 4);
            r[10] = *(const f32x4*)(pu + rstep + ko);  r[11] = *(const f32x4*)(pu + rstep + ko + 4);
        }

        // compute current buffer
        short8 bg[4], bu[4], af[4];
        #pragma unroll
        for (int ni = 0; ni < 4; ++ni) {
            bg[ni] = *(const short8*)&Gs[cur][(wc + ni * 16 + r16) * 32 + kg * 8];
            bu[ni] = *(const short8*)&Us[cur][(wc + ni * 16 + r16) * 32 + kg * 8];
        }
        #pragma unroll
        for (int mi = 0; mi < 4; ++mi)
            af[mi] = *(const short8*)&As[cur][(wr + mi * 16 + r16) * 32 + kg * 8];

        #pragma unroll
        for (int mi = 0; mi < 4; ++mi)
            #pragma unroll
            for (int ni = 0; ni < 4; ++ni) {
                accg[mi][ni] = __builtin_amdgcn_mfma_f32_16x16x32_bf16(af[mi], bg[ni], accg[mi][ni], 0, 0, 0);
                accu[mi][ni] = __builtin_amdgcn_mfma_f32_16x16x32_bf16(af[mi], bu[ni], accu[mi][ni], 0, 0, 0);
            }

        if (more) {
            const int nb = cur ^ 1;
            cvt_store(&As[nb][tid * 8],        r[0],  r[1]);
            cvt_store(&As[nb][tid * 8 + 2048], r[2],  r[3]);
            cvt_store(&Gs[nb][tid * 8],        r[4],  r[5]);
            cvt_store(&Gs[nb][tid * 8 + 2048], r[6],  r[7]);
            cvt_store(&Us[nb][tid * 8],        r[8],  r[9]);
            cvt_store(&Us[nb][tid * 8 + 2048], r[10], r[11]);
        }
        __syncthreads();
        cur ^= 1;
    }

    // epilogue: silu(gate)*up -> bf16 inter
    #pragma unroll
    for (int mi = 0; mi < 4; ++mi)
        #pragma unroll
        for (int ni = 0; ni < 4; ++ni) {
            f32x4 g = accg[mi][ni], u = accu[mi][ni];
            const int col = n0 + wc + ni * 16 + r16;
            const int rb  = m0 + wr + mi * 16 + kg * 4;
            #pragma unroll
            for (int rr = 0; rr < 4; ++rr) {
                float gv = g[rr];
                float s  = gv / (1.0f + __expf(-gv));
                inter[(size_t)(rb + rr) * Id + col] = f2bf(s * u[rr]);
            }
        }
}

// ---------------------------------------------------------------------------
// Kernel 2: out[m,h] = inter[m,:] . wd[h,:]   (bf16 A from ws, fp32 B, fp32 out)
// 128x128 tile over (M, H), K = Id.
// ---------------------------------------------------------------------------
__global__ __launch_bounds__(256, 2) void k_down(
    const unsigned short* __restrict__ inter, const float* __restrict__ wd,
    float* __restrict__ out)
{
    __shared__ unsigned short As[2][4096];
    __shared__ unsigned short Bs[2][4096];

    const int tid = threadIdx.x;
    const int nwg = gridDim.x;                      // 2048, %8==0
    const int bid = blockIdx.x;
    const int swz = (bid & 7) * (nwg >> 3) + (bid >> 3);
    const int m0 = (swz & 63) * 128;
    const int n0 = (swz >> 6) * 128;

    const int lane = tid & 63;
    const int wid  = tid >> 6;
    const int wr   = (wid >> 1) << 6;
    const int wc   = (wid & 1) << 6;
    const int r16  = lane & 15;
    const int kg   = lane >> 4;

    const int srow = tid >> 2;
    const int sc8  = (tid & 3) * 8;
    const unsigned short* pa = inter + (size_t)(m0 + srow) * Id + sc8;
    const float* pb = wd + (size_t)(n0 + srow) * Id + sc8;
    const size_t rstepA = (size_t)64 * Id;
    const size_t rstepB = (size_t)64 * Id;

    f32x4 acc[4][4] = {};

    {
        short8 a0 = *(const short8*)(pa);
        short8 a1 = *(const short8*)(pa + rstepA);
        f32x4 b0 = *(const f32x4*)(pb);          f32x4 b1 = *(const f32x4*)(pb + 4);
        f32x4 b2 = *(const f32x4*)(pb + rstepB); f32x4 b3 = *(const f32x4*)(pb + rstepB + 4);
        *reinterpret_cast<short8*>(&As[0][tid * 8])        = a0;
        *reinterpret_cast<short8*>(&As[0][tid * 8 + 2048]) = a1;
        cvt_store(&Bs[0][tid * 8],        b0, b1);
        cvt_store(&Bs[0][tid * 8 + 2048], b2, b3);
    }
    __syncthreads();

    const int NK = Id / 32;   // 344
    int cur = 0;
    for (int kt = 0; kt < NK; ++kt) {
        const bool more = (kt + 1) < NK;
        short8 ra0, ra1;
        f32x4 rb[4];
        if (more) {
            const int ko = (kt + 1) * 32;
            ra0 = *(const short8*)(pa + ko);
            ra1 = *(const short8*)(pa + rstepA + ko);
            rb[0] = *(const f32x4*)(pb + ko);           rb[1] = *(const f32x4*)(pb + ko + 4);
            rb[2] = *(const f32x4*)(pb + rstepB + ko);  rb[3] = *(const f32x4*)(pb + rstepB + ko + 4);
        }

        short8 bf[4], af[4];
        #pragma unroll
        for (int ni = 0; ni < 4; ++ni)
            bf[ni] = *(const short8*)&Bs[cur][(wc + ni * 16 + r16) * 32 + kg * 8];
        #pragma unroll
        for (int mi = 0; mi < 4; ++mi)
            af[mi] = *(const short8*)&As[cur][(wr + mi * 16 + r16) * 32 + kg * 8];

        #pragma unroll
        for (int mi = 0; mi < 4; ++mi)
            #pragma unroll
            for (int ni = 0; ni < 4; ++ni)
                acc[mi][ni] = __builtin_amdgcn_mfma_f32_16x16x32_bf16(af[mi], bf[ni], acc[mi][ni], 0, 0, 0);

        if (more) {
            const int nb = cur ^ 1;
            *reinterpret_cast<short8*>(&As[nb][tid * 8])        = ra0;
            *reinterpret_cast<short8*>(&As[nb][tid * 8 + 2048]) = ra1;
            cvt_store(&Bs[nb][tid * 8],        rb[0], rb[1]);
            cvt_store(&Bs[nb][tid * 8 + 2048], rb[2], rb[3]);
        }
        __syncthreads();
        cur ^= 1;
    }

    #pragma unroll
    for (int mi = 0; mi < 4; ++mi)
        #pragma unroll
        for (int ni = 0; ni < 4; ++ni) {
            f32x4 v = acc[mi][ni];
            const int col = n0 + wc + ni * 16 + r16;
            const int rb_ = m0 + wr + mi * 16 + kg * 4;
            #pragma unroll
            for (int rr = 0; rr < 4; ++rr)
                out[(size_t)(rb_ + rr) * Hd + col] = v[rr];
        }
}

extern "C" void kernel_launch(void* const* d_in, const int* in_sizes, int n_in,
                              void* d_out, int out_size, void* d_ws, size_t ws_size,
                              hipStream_t stream) {
    const float* x  = (const float*)d_in[0];
    const float* wg = (const float*)d_in[1];
    const float* wu = (const float*)d_in[2];
    const float* wd = (const float*)d_in[3];
    float* out = (float*)d_out;
    unsigned short* inter = (unsigned short*)d_ws;   // M x I bf16 = 180.4 MB

    k_gateup<<<dim3((Md / 128) * (Id / 128)), dim3(256), 0, stream>>>(x, wg, wu, inter);
    k_down  <<<dim3((Md / 128) * (Hd / 128)), dim3(256), 0, stream>>>(inter, wd, out);
}

// Round 2
// 3065.945 us; speedup vs baseline: 1.2521x; 1.2521x over previous
//
#include <hip/hip_runtime.h>
#include <hip/hip_bf16.h>
#include <stdint.h>

// B,S,H,I = 4,2048,4096,11008 ; M = B*S = 8192
static constexpr int Hd = 4096;
static constexpr int Id = 11008;
static constexpr int Md = 8192;
static constexpr int LDA = 40;   // LDS row stride in shorts (80 B) -> 2-way bank alias (free)

using short8 = __attribute__((ext_vector_type(8))) short;
using f32x4  = __attribute__((ext_vector_type(4))) float;

__device__ __forceinline__ unsigned short f2bf(float x) {
    union { float f; unsigned u; } v; v.f = x;
    unsigned r = v.u + 0x7FFF + ((v.u >> 16) & 1);   // RNE
    return (unsigned short)(r >> 16);
}

__device__ __forceinline__ void cvt_store(unsigned short* dst, const f32x4& a, const f32x4& b) {
    short8 v;
    v[0] = (short)f2bf(a[0]); v[1] = (short)f2bf(a[1]);
    v[2] = (short)f2bf(a[2]); v[3] = (short)f2bf(a[3]);
    v[4] = (short)f2bf(b[0]); v[5] = (short)f2bf(b[1]);
    v[6] = (short)f2bf(b[2]); v[7] = (short)f2bf(b[3]);
    *reinterpret_cast<short8*>(dst) = v;
}

// ---------------------------------------------------------------------------
// fp32 -> bf16 bulk converter (grid-stride over 8-element chunks)
// ---------------------------------------------------------------------------
__global__ __launch_bounds__(256) void k_cvt(const float* __restrict__ in,
                                             unsigned short* __restrict__ out, int n8) {
    int i = blockIdx.x * blockDim.x + threadIdx.x;
    const int stride = gridDim.x * blockDim.x;
    for (; i < n8; i += stride) {
        f32x4 a = *(const f32x4*)(in + (size_t)i * 8);
        f32x4 b = *(const f32x4*)(in + (size_t)i * 8 + 4);
        cvt_store(out + (size_t)i * 8, a, b);
    }
}

// ---------------------------------------------------------------------------
// Kernel 1: inter[m,i] = silu(x.wg^T) * (x.wu^T)   (bf16 out to workspace)
// 128x128 tile over (M, I), K = Hd. 256 threads = 4 waves (2x2), 64x64/wave.
// BF16 = inputs pre-converted to bf16 (fast path); else fp32 with on-the-fly cvt.
// ---------------------------------------------------------------------------
template<bool BF16>
__global__ __launch_bounds__(256, 2) void k_gateup(
    const void* __restrict__ xv, const void* __restrict__ wgv,
    const void* __restrict__ wuv, unsigned short* __restrict__ inter)
{
    __shared__ unsigned short As[2][128 * LDA];
    __shared__ unsigned short Gs[2][128 * LDA];
    __shared__ unsigned short Us[2][128 * LDA];

    const int tid = threadIdx.x;
    const int nwg = gridDim.x;                      // 5504, %8==0
    const int bid = blockIdx.x;
    const int swz = (bid & 7) * (nwg >> 3) + (bid >> 3);   // XCD swizzle
    const int m0 = (swz & 63) * 128;                // m fastest -> weight panel reuse
    const int n0 = (swz >> 6) * 128;

    const int lane = tid & 63;
    const int wid  = tid >> 6;
    const int wr   = (wid >> 1) << 6;   // wave row offset in tile
    const int wc   = (wid & 1) << 6;    // wave col offset
    const int r16  = lane & 15;
    const int kg   = lane >> 4;         // k-group 0..3

    // staging: thread handles 16B(bf16)/32B(f32) chunks at rows {tid>>2, +64}, col8 (tid&3)*8
    const int srow = tid >> 2;
    const int sc8  = (tid & 3) * 8;
    const int d0 = srow * LDA + sc8;
    const int d1 = (srow + 64) * LDA + sc8;

    const size_t offA = (size_t)(m0 + srow) * Hd + sc8;
    const size_t offB = (size_t)(n0 + srow) * Hd + sc8;
    const size_t rstep = (size_t)64 * Hd;

    f32x4 accg[4][4] = {};
    f32x4 accu[4][4] = {};

    // prologue: stage k-tile 0 into buffer 0
    if constexpr (BF16) {
        const unsigned short* x = (const unsigned short*)xv;
        const unsigned short* g = (const unsigned short*)wgv;
        const unsigned short* u = (const unsigned short*)wuv;
        *(short8*)&As[0][d0] = *(const short8*)(x + offA);
        *(short8*)&As[0][d1] = *(const short8*)(x + offA + rstep);
        *(short8*)&Gs[0][d0] = *(const short8*)(g + offB);
        *(short8*)&Gs[0][d1] = *(const short8*)(g + offB + rstep);
        *(short8*)&Us[0][d0] = *(const short8*)(u + offB);
        *(short8*)&Us[0][d1] = *(const short8*)(u + offB + rstep);
    } else {
        const float* x = (const float*)xv;
        const float* g = (const float*)wgv;
        const float* u = (const float*)wuv;
        cvt_store(&As[0][d0], *(const f32x4*)(x + offA),         *(const f32x4*)(x + offA + 4));
        cvt_store(&As[0][d1], *(const f32x4*)(x + offA + rstep), *(const f32x4*)(x + offA + rstep + 4));
        cvt_store(&Gs[0][d0], *(const f32x4*)(g + offB),         *(const f32x4*)(g + offB + 4));
        cvt_store(&Gs[0][d1], *(const f32x4*)(g + offB + rstep), *(const f32x4*)(g + offB + rstep + 4));
        cvt_store(&Us[0][d0], *(const f32x4*)(u + offB),         *(const f32x4*)(u + offB + 4));
        cvt_store(&Us[0][d1], *(const f32x4*)(u + offB + rstep), *(const f32x4*)(u + offB + rstep + 4));
    }
    __syncthreads();

    const int NK = Hd / 32;   // 128
    int cur = 0;
    for (int kt = 0; kt < NK; ++kt) {
        const bool more = (kt + 1) < NK;
        short8 ra[6];
        f32x4  rf[12];
        if (more) {
            const int ko = (kt + 1) * 32;
            if constexpr (BF16) {
                const unsigned short* x = (const unsigned short*)xv;
                const unsigned short* g = (const unsigned short*)wgv;
                const unsigned short* u = (const unsigned short*)wuv;
                ra[0] = *(const short8*)(x + offA + ko);
                ra[1] = *(const short8*)(x + offA + rstep + ko);
                ra[2] = *(const short8*)(g + offB + ko);
                ra[3] = *(const short8*)(g + offB + rstep + ko);
                ra[4] = *(const short8*)(u + offB + ko);
                ra[5] = *(const short8*)(u + offB + rstep + ko);
            } else {
                const float* x = (const float*)xv;
                const float* g = (const float*)wgv;
                const float* u = (const float*)wuv;
                rf[0]  = *(const f32x4*)(x + offA + ko);          rf[1]  = *(const f32x4*)(x + offA + ko + 4);
                rf[2]  = *(const f32x4*)(x + offA + rstep + ko);  rf[3]  = *(const f32x4*)(x + offA + rstep + ko + 4);
                rf[4]  = *(const f32x4*)(g + offB + ko);          rf[5]  = *(const f32x4*)(g + offB + ko + 4);
                rf[6]  = *(const f32x4*)(g + offB + rstep + ko);  rf[7]  = *(const f32x4*)(g + offB + rstep + ko + 4);
                rf[8]  = *(const f32x4*)(u + offB + ko);          rf[9]  = *(const f32x4*)(u + offB + ko + 4);
                rf[10] = *(const f32x4*)(u + offB + rstep + ko);  rf[11] = *(const f32x4*)(u + offB + rstep + ko + 4);
            }
        }

        // compute current buffer
        short8 bg[4], bu[4], af[4];
        #pragma unroll
        for (int ni = 0; ni < 4; ++ni) {
            bg[ni] = *(const short8*)&Gs[cur][(wc + ni * 16 + r16) * LDA + kg * 8];
            bu[ni] = *(const short8*)&Us[cur][(wc + ni * 16 + r16) * LDA + kg * 8];
        }
        #pragma unroll
        for (int mi = 0; mi < 4; ++mi)
            af[mi] = *(const short8*)&As[cur][(wr + mi * 16 + r16) * LDA + kg * 8];

        #pragma unroll
        for (int mi = 0; mi < 4; ++mi)
            #pragma unroll
            for (int ni = 0; ni < 4; ++ni) {
                accg[mi][ni] = __builtin_amdgcn_mfma_f32_16x16x32_bf16(af[mi], bg[ni], accg[mi][ni], 0, 0, 0);
                accu[mi][ni] = __builtin_amdgcn_mfma_f32_16x16x32_bf16(af[mi], bu[ni], accu[mi][ni], 0, 0, 0);
            }

        if (more) {
            const int nb = cur ^ 1;
            if constexpr (BF16) {
                *(short8*)&As[nb][d0] = ra[0];
                *(short8*)&As[nb][d1] = ra[1];
                *(short8*)&Gs[nb][d0] = ra[2];
                *(short8*)&Gs[nb][d1] = ra[3];
                *(short8*)&Us[nb][d0] = ra[4];
                *(short8*)&Us[nb][d1] = ra[5];
            } else {
                cvt_store(&As[nb][d0], rf[0],  rf[1]);
                cvt_store(&As[nb][d1], rf[2],  rf[3]);
                cvt_store(&Gs[nb][d0], rf[4],  rf[5]);
                cvt_store(&Gs[nb][d1], rf[6],  rf[7]);
                cvt_store(&Us[nb][d0], rf[8],  rf[9]);
                cvt_store(&Us[nb][d1], rf[10], rf[11]);
            }
        }
        __syncthreads();
        cur ^= 1;
    }

    // epilogue: silu(gate)*up -> bf16 inter
    #pragma unroll
    for (int mi = 0; mi < 4; ++mi)
        #pragma unroll
        for (int ni = 0; ni < 4; ++ni) {
            f32x4 g = accg[mi][ni], u = accu[mi][ni];
            const int col = n0 + wc + ni * 16 + r16;
            const int rb  = m0 + wr + mi * 16 + kg * 4;
            #pragma unroll
            for (int rr = 0; rr < 4; ++rr) {
                float gv = g[rr];
                float s  = gv / (1.0f + __expf(-gv));
                inter[(size_t)(rb + rr) * Id + col] = f2bf(s * u[rr]);
            }
        }
}

// ---------------------------------------------------------------------------
// Kernel 2: out[m,h] = inter[m,:] . wd[h,:]   (bf16 A from ws, fp32 out)
// 128x128 tile over (M, H), K = Id.
// ---------------------------------------------------------------------------
template<bool BF16>
__global__ __launch_bounds__(256, 3) void k_down(
    const unsigned short* __restrict__ inter, const void* __restrict__ wdv,
    float* __restrict__ out)
{
    __shared__ unsigned short As[2][128 * LDA];
    __shared__ unsigned short Bs[2][128 * LDA];

    const int tid = threadIdx.x;
    const int nwg = gridDim.x;                      // 2048, %8==0
    const int bid = blockIdx.x;
    const int swz = (bid & 7) * (nwg >> 3) + (bid >> 3);
    const int m0 = (swz & 63) * 128;
    const int n0 = (swz >> 6) * 128;

    const int lane = tid & 63;
    const int wid  = tid >> 6;
    const int wr   = (wid >> 1) << 6;
    const int wc   = (wid & 1) << 6;
    const int r16  = lane & 15;
    const int kg   = lane >> 4;

    const int srow = tid >> 2;
    const int sc8  = (tid & 3) * 8;
    const int d0 = srow * LDA + sc8;
    const int d1 = (srow + 64) * LDA + sc8;

    const size_t offA = (size_t)(m0 + srow) * Id + sc8;
    const size_t offB = (size_t)(n0 + srow) * Id + sc8;
    const size_t rstep = (size_t)64 * Id;

    f32x4 acc[4][4] = {};

    {
        *(short8*)&As[0][d0] = *(const short8*)(inter + offA);
        *(short8*)&As[0][d1] = *(const short8*)(inter + offA + rstep);
        if constexpr (BF16) {
            const unsigned short* w = (const unsigned short*)wdv;
            *(short8*)&Bs[0][d0] = *(const short8*)(w + offB);
            *(short8*)&Bs[0][d1] = *(const short8*)(w + offB + rstep);
        } else {
            const float* w = (const float*)wdv;
            cvt_store(&Bs[0][d0], *(const f32x4*)(w + offB),         *(const f32x4*)(w + offB + 4));
            cvt_store(&Bs[0][d1], *(const f32x4*)(w + offB + rstep), *(const f32x4*)(w + offB + rstep + 4));
        }
    }
    __syncthreads();

    const int NK = Id / 32;   // 344
    int cur = 0;
    for (int kt = 0; kt < NK; ++kt) {
        const bool more = (kt + 1) < NK;
        short8 ra0, ra1, rb0, rb1;
        f32x4 rw[4];
        if (more) {
            const int ko = (kt + 1) * 32;
            ra0 = *(const short8*)(inter + offA + ko);
            ra1 = *(const short8*)(inter + offA + rstep + ko);
            if constexpr (BF16) {
                const unsigned short* w = (const unsigned short*)wdv;
                rb0 = *(const short8*)(w + offB + ko);
                rb1 = *(const short8*)(w + offB + rstep + ko);
            } else {
                const float* w = (const float*)wdv;
                rw[0] = *(const f32x4*)(w + offB + ko);          rw[1] = *(const f32x4*)(w + offB + ko + 4);
                rw[2] = *(const f32x4*)(w + offB + rstep + ko);  rw[3] = *(const f32x4*)(w + offB + rstep + ko + 4);
            }
        }

        short8 bf[4], af[4];
        #pragma unroll
        for (int ni = 0; ni < 4; ++ni)
            bf[ni] = *(const short8*)&Bs[cur][(wc + ni * 16 + r16) * LDA + kg * 8];
        #pragma unroll
        for (int mi = 0; mi < 4; ++mi)
            af[mi] = *(const short8*)&As[cur][(wr + mi * 16 + r16) * LDA + kg * 8];

        #pragma unroll
        for (int mi = 0; mi < 4; ++mi)
            #pragma unroll
            for (int ni = 0; ni < 4; ++ni)
                acc[mi][ni] = __builtin_amdgcn_mfma_f32_16x16x32_bf16(af[mi], bf[ni], acc[mi][ni], 0, 0, 0);

        if (more) {
            const int nb = cur ^ 1;
            *(short8*)&As[nb][d0] = ra0;
            *(short8*)&As[nb][d1] = ra1;
            if constexpr (BF16) {
                *(short8*)&Bs[nb][d0] = rb0;
                *(short8*)&Bs[nb][d1] = rb1;
            } else {
                cvt_store(&Bs[nb][d0], rw[0], rw[1]);
                cvt_store(&Bs[nb][d1], rw[2], rw[3]);
            }
        }
        __syncthreads();
        cur ^= 1;
    }

    #pragma unroll
    for (int mi = 0; mi < 4; ++mi)
        #pragma unroll
        for (int ni = 0; ni < 4; ++ni) {
            f32x4 v = acc[mi][ni];
            const int col = n0 + wc + ni * 16 + r16;
            const int rb_ = m0 + wr + mi * 16 + kg * 4;
            #pragma unroll
            for (int rr = 0; rr < 4; ++rr)
                out[(size_t)(rb_ + rr) * Hd + col] = v[rr];
        }
}

extern "C" void kernel_launch(void* const* d_in, const int* in_sizes, int n_in,
                              void* d_out, int out_size, void* d_ws, size_t ws_size,
                              hipStream_t stream) {
    const float* x  = (const float*)d_in[0];
    const float* wg = (const float*)d_in[1];
    const float* wu = (const float*)d_in[2];
    const float* wd = (const float*)d_in[3];
    float* out = (float*)d_out;

    unsigned short* inter = (unsigned short*)d_ws;       // M x I bf16 = 180.4 MB
    const size_t interB = (size_t)Md * Id * 2;
    const size_t xbB    = (size_t)Md * Hd * 2;
    const size_t wB     = (size_t)Id * Hd * 2;
    const size_t need   = interB + xbB + 3 * wB;         // ~495 MB

    if (ws_size >= need) {
        unsigned short* xb  = (unsigned short*)((char*)d_ws + interB);
        unsigned short* wgb = xb  + (size_t)Md * Hd;
        unsigned short* wub = wgb + (size_t)Id * Hd;
        unsigned short* wdb = wub + (size_t)Id * Hd;
        k_cvt<<<dim3(2048), dim3(256), 0, stream>>>(x,  xb,  Md * Hd / 8);
        k_cvt<<<dim3(2048), dim3(256), 0, stream>>>(wg, wgb, Id * Hd / 8);
        k_cvt<<<dim3(2048), dim3(256), 0, stream>>>(wu, wub, Id * Hd / 8);
        k_cvt<<<dim3(2048), dim3(256), 0, stream>>>(wd, wdb, Id * Hd / 8);
        k_gateup<true><<<dim3((Md / 128) * (Id / 128)), dim3(256), 0, stream>>>(xb, wgb, wub, inter);
        k_down<true>  <<<dim3((Md / 128) * (Hd / 128)), dim3(256), 0, stream>>>(inter, wdb, out);
    } else {
        k_gateup<false><<<dim3((Md / 128) * (Id / 128)), dim3(256), 0, stream>>>(x, wg, wu, inter);
        k_down<false>  <<<dim3((Md / 128) * (Hd / 128)), dim3(256), 0, stream>>>(inter, wd, out);
    }
}